// Round 1
// baseline (717.986 us; speedup 1.0000x reference)
//
#include <hip/hip_runtime.h>
#include <stdint.h>
#include <math.h>

// Problem constants (DBRX FFN): B=2 S=2048 D=1024 E=8 F=2048 K=2
#define NB 2
#define NS 2048
#define ND 1024
#define NE 8
#define NF 2048
#define NTOK (NB*NS)          // 4096 tokens
#define EFD ((size_t)NE*NF*ND)

typedef short bf16x8 __attribute__((ext_vector_type(8)));
typedef float f32x4 __attribute__((ext_vector_type(4)));

__device__ __forceinline__ unsigned short f2bf(float f) {
  unsigned u = __float_as_uint(f);
  unsigned r = (u + 0x7FFFu + ((u >> 16) & 1u)) >> 16;
  return (unsigned short)r;
}
__device__ __forceinline__ float bf2f(unsigned short s) {
  return __uint_as_float(((unsigned)s) << 16);
}

// ---------------- convert fp32 -> bf16 (vectorized) ----------------
__global__ void cvt_bf16(const float* __restrict__ src,
                         unsigned short* __restrict__ dst, int n4) {
  int i = blockIdx.x * blockDim.x + threadIdx.x;
  int stride = gridDim.x * blockDim.x;
  for (; i < n4; i += stride) {
    float4 v = ((const float4*)src)[i];
    ushort4 o;
    o.x = f2bf(v.x); o.y = f2bf(v.y); o.z = f2bf(v.z); o.w = f2bf(v.w);
    ((ushort4*)dst)[i] = o;
  }
}

// ---------------- transpose w2 (E,F,D) fp32 -> w2t (E,D,F) bf16 ----------------
__global__ void transpose_w2(const float* __restrict__ w2,
                             unsigned short* __restrict__ w2t) {
  __shared__ float tile[32][33];
  int e = blockIdx.z;
  int d0 = blockIdx.x * 32, f0 = blockIdx.y * 32;
  int tx = threadIdx.x, ty = threadIdx.y;
  const float* src = w2 + (size_t)e * NF * ND;
  unsigned short* dst = w2t + (size_t)e * ND * NF;
#pragma unroll
  for (int i = ty; i < 32; i += 8)
    tile[i][tx] = src[(size_t)(f0 + i) * ND + d0 + tx];
  __syncthreads();
#pragma unroll
  for (int i = ty; i < 32; i += 8)
    dst[(size_t)(d0 + i) * NF + f0 + tx] = f2bf(tile[tx][i]);
}

// ---------------- router: logits, softmax, top-2, lists ----------------
__global__ void router_kernel(const float* __restrict__ hs,
                              const float* __restrict__ rk,
                              float* __restrict__ wout,   // [NTOK][NE] softmax probs
                              float* __restrict__ tw,     // [NTOK][2] normalized top weights
                              int* __restrict__ counts,   // [NE]
                              int* __restrict__ list) {   // [NE][NTOK] entries (t<<1)|slot
  int t = blockIdx.x;
  int lane = threadIdx.x;
  const float* row = hs + (size_t)t * ND;
  float acc[NE];
#pragma unroll
  for (int e = 0; e < NE; ++e) acc[e] = 0.f;
  for (int d = lane; d < ND; d += 64) {
    float x = row[d];
    const float* r = rk + (size_t)d * NE;
#pragma unroll
    for (int e = 0; e < NE; ++e) acc[e] += x * r[e];
  }
#pragma unroll
  for (int off = 32; off > 0; off >>= 1) {
#pragma unroll
    for (int e = 0; e < NE; ++e) acc[e] += __shfl_xor(acc[e], off, 64);
  }
  if (lane == 0) {
    float mx = acc[0]; int i0 = 0;
#pragma unroll
    for (int e = 1; e < NE; ++e) if (acc[e] > mx) { mx = acc[e]; i0 = e; }
    float m2 = -3.4e38f; int i1 = 0;
#pragma unroll
    for (int e = 0; e < NE; ++e) if (e != i0 && acc[e] > m2) { m2 = acc[e]; i1 = e; }
    float p[NE]; float den = 0.f;
#pragma unroll
    for (int e = 0; e < NE; ++e) { p[e] = expf(acc[e] - mx); den += p[e]; }
    float inv = 1.f / den;
#pragma unroll
    for (int e = 0; e < NE; ++e) { p[e] *= inv; wout[t * NE + e] = p[e]; }
    float w0 = p[i0], w1 = p[i1];
    float s = 1.f / (w0 + w1);
    tw[t * 2 + 0] = w0 * s;
    tw[t * 2 + 1] = w1 * s;
    int pos0 = atomicAdd(&counts[i0], 1);
    list[i0 * NTOK + pos0] = (t << 1);
    int pos1 = atomicAdd(&counts[i1], 1);
    list[i1 * NTOK + pos1] = (t << 1) | 1;
  }
}

// ---------------- gathered NT GEMM with MFMA ----------------
// block = 256 threads = 4 waves (2x2), block tile 128x128, wave tile 64x64
// A rows gathered via per-expert list. C rows addressed by (slot,token).
// mode 0: store acc as bf16 to Cb (x1)
// mode 1: h = silu(X1)*acc -> bf16 Cb
// mode 2: store acc fp32 to Cf (y)
__global__ __launch_bounds__(256) void gemm_nt(
    const int* __restrict__ counts, const int* __restrict__ list,
    const unsigned short* __restrict__ A, int lda, int aRowMode,
    const unsigned short* __restrict__ B, long bStrideE, int ldb,
    int nTilesN, int kTiles, int mode,
    unsigned short* __restrict__ Cb,
    const unsigned short* __restrict__ X1,
    float* __restrict__ Cf, int ldc) {
  int bid = blockIdx.x;
  int e = bid / (32 * nTilesN);
  int rem = bid - e * 32 * nTilesN;
  int mt = rem / nTilesN;
  int nt = rem - mt * nTilesN;
  int cnt = counts[e];
  if (mt * 128 >= cnt) return;

  int tid = threadIdx.x;
  int wid = tid >> 6, lane = tid & 63;
  int wr = wid >> 1, wc = wid & 1;
  int rowbase = mt * 128 + wr * 64;
  int colbase = nt * 128 + wc * 64;
  const int* mylist = list + e * NTOK;
  int l15 = lane & 15, l4 = lane >> 4;

  const unsigned short* aptr[4];
#pragma unroll
  for (int mi = 0; mi < 4; ++mi) {
    int r = rowbase + mi * 16 + l15;
    if (r >= cnt) r = cnt - 1;
    int entry = mylist[r];
    int tok = entry >> 1, slot = entry & 1;
    long arow = aRowMode ? ((long)slot * NTOK + tok) : (long)tok;
    aptr[mi] = A + arow * lda + l4 * 8;
  }
  const unsigned short* bbase = B + (long)e * bStrideE;
  const unsigned short* bptr[4];
#pragma unroll
  for (int ni = 0; ni < 4; ++ni) {
    int c = colbase + ni * 16 + l15;
    bptr[ni] = bbase + (long)c * ldb + l4 * 8;
  }

  f32x4 acc[4][4];
#pragma unroll
  for (int mi = 0; mi < 4; ++mi)
#pragma unroll
    for (int ni = 0; ni < 4; ++ni) {
      f32x4 z = {0.f, 0.f, 0.f, 0.f};
      acc[mi][ni] = z;
    }

  for (int kt = 0; kt < kTiles; ++kt) {
    int kk = kt * 32;
    bf16x8 af[4], bfr[4];
#pragma unroll
    for (int mi = 0; mi < 4; ++mi)
      af[mi] = *reinterpret_cast<const bf16x8*>(aptr[mi] + kk);
#pragma unroll
    for (int ni = 0; ni < 4; ++ni)
      bfr[ni] = *reinterpret_cast<const bf16x8*>(bptr[ni] + kk);
#pragma unroll
    for (int mi = 0; mi < 4; ++mi)
#pragma unroll
      for (int ni = 0; ni < 4; ++ni)
        acc[mi][ni] = __builtin_amdgcn_mfma_f32_16x16x32_bf16(
            af[mi], bfr[ni], acc[mi][ni], 0, 0, 0);
  }

  // epilogue: C/D layout col=lane&15, row=(lane>>4)*4+j
#pragma unroll
  for (int mi = 0; mi < 4; ++mi) {
#pragma unroll
    for (int j = 0; j < 4; ++j) {
      int r = rowbase + mi * 16 + l4 * 4 + j;
      if (r >= cnt) continue;
      int entry = mylist[r];
      int tok = entry >> 1, slot = entry & 1;
      long crow = (long)slot * NTOK + tok;
      if (mode == 0) {
#pragma unroll
        for (int ni = 0; ni < 4; ++ni) {
          int c = colbase + ni * 16 + l15;
          Cb[crow * ldc + c] = f2bf(acc[mi][ni][j]);
        }
      } else if (mode == 1) {
#pragma unroll
        for (int ni = 0; ni < 4; ++ni) {
          int c = colbase + ni * 16 + l15;
          float x1 = bf2f(X1[crow * ldc + c]);
          float x2 = acc[mi][ni][j];
          float h = (x1 / (1.f + expf(-x1))) * x2;
          Cb[crow * ldc + c] = f2bf(h);
        }
      } else {
#pragma unroll
        for (int ni = 0; ni < 4; ++ni) {
          int c = colbase + ni * 16 + l15;
          Cf[crow * ldc + c] = acc[mi][ni][j];
        }
      }
    }
  }
}

// ---------------- combine: out = tw0*y0 + tw1*y1 ----------------
__global__ void combine_kernel(const float* __restrict__ ybuf,
                               const float* __restrict__ tw,
                               float* __restrict__ out) {
  int i = blockIdx.x * blockDim.x + threadIdx.x;
  const int total = NTOK * ND / 4;
  int stride = gridDim.x * blockDim.x;
  for (; i < total; i += stride) {
    int t = i >> 8;  // ND/4 = 256 quads per token
    float w0 = tw[t * 2], w1 = tw[t * 2 + 1];
    float4 y0 = ((const float4*)ybuf)[i];
    float4 y1 = ((const float4*)(ybuf + (size_t)NTOK * ND))[i];
    float4 o;
    o.x = w0 * y0.x + w1 * y1.x;
    o.y = w0 * y0.y + w1 * y1.y;
    o.z = w0 * y0.z + w1 * y1.z;
    o.w = w0 * y0.w + w1 * y1.w;
    ((float4*)out)[i] = o;
  }
}

// ---------------- workspace layout (bytes) ----------------
// counts:   0        (256)
// list:     256      (8*4096*4 = 131072)        end 131328
// tw:       131328   (4096*2*4 = 32768)         end 164096
// hsb:      164096   (4096*1024*2 = 8388608)    end 8552704
// w1b:      8552704  (33554432)                 end 42107136
// v1b:      42107136 (33554432)                 end 75661568
// w2t:      75661568 (33554432)                 end 109216000
// x1buf:    109216000 (2*4096*2048*2 = 33554432) end 142770432
// hbuf:     142770432 (33554432)                end 176324864
// ybuf:     176324864 (2*4096*1024*4 = 33554432) end 209879296

extern "C" void kernel_launch(void* const* d_in, const int* in_sizes, int n_in,
                              void* d_out, int out_size, void* d_ws, size_t ws_size,
                              hipStream_t stream) {
  const float* hs = (const float*)d_in[0];
  const float* rk = (const float*)d_in[1];
  const float* w1 = (const float*)d_in[2];
  const float* v1 = (const float*)d_in[3];
  const float* w2 = (const float*)d_in[4];
  float* out = (float*)d_out;
  float* wout = out + (size_t)NTOK * ND;  // weights output [NTOK][NE]

  char* ws = (char*)d_ws;
  int* counts = (int*)(ws + 0);
  int* list = (int*)(ws + 256);
  float* tw = (float*)(ws + 131328);
  unsigned short* hsb = (unsigned short*)(ws + 164096);
  unsigned short* w1b = (unsigned short*)(ws + 8552704);
  unsigned short* v1b = (unsigned short*)(ws + 42107136);
  unsigned short* w2t = (unsigned short*)(ws + 75661568);
  unsigned short* x1buf = (unsigned short*)(ws + 109216000);
  unsigned short* hbuf = (unsigned short*)(ws + 142770432);
  float* ybuf = (float*)(ws + 176324864);

  hipMemsetAsync(counts, 0, 256, stream);

  // fp32 -> bf16 conversions
  cvt_bf16<<<2048, 256, 0, stream>>>(hs, hsb, NTOK * ND / 4);
  cvt_bf16<<<4096, 256, 0, stream>>>(w1, w1b, (int)(EFD / 4));
  cvt_bf16<<<4096, 256, 0, stream>>>(v1, v1b, (int)(EFD / 4));
  transpose_w2<<<dim3(ND / 32, NF / 32, NE), dim3(32, 8), 0, stream>>>(w2, w2t);

  router_kernel<<<NTOK, 64, 0, stream>>>(hs, rk, wout, tw, counts, list);

  // pass1: x1 = X @ w1^T   (K=1024, N=2048)
  gemm_nt<<<NE * 32 * 16, 256, 0, stream>>>(
      counts, list, hsb, ND, 0, w1b, (long)NF * ND, ND,
      16, ND / 32, 0, x1buf, nullptr, nullptr, NF);
  // pass2: x2 = X @ v1^T, h = silu(x1)*x2
  gemm_nt<<<NE * 32 * 16, 256, 0, stream>>>(
      counts, list, hsb, ND, 0, v1b, (long)NF * ND, ND,
      16, ND / 32, 1, hbuf, x1buf, nullptr, NF);
  // pass3: y = h @ w2t^T   (K=2048, N=1024)
  gemm_nt<<<NE * 32 * 8, 256, 0, stream>>>(
      counts, list, hbuf, NF, 1, w2t, (long)ND * NF, NF,
      8, NF / 32, 2, nullptr, nullptr, ybuf, ND);

  combine_kernel<<<2048, 256, 0, stream>>>(ybuf, tw, out);
}

// Round 2
// 403.445 us; speedup vs baseline: 1.7796x; 1.7796x over previous
//
#include <hip/hip_runtime.h>
#include <stdint.h>
#include <math.h>

// Problem constants (DBRX FFN): B=2 S=2048 D=1024 E=8 F=2048 K=2
#define NB 2
#define NS 2048
#define ND 1024
#define NE 8
#define NF 2048
#define NTOK (NB*NS)          // 4096 tokens
#define EFD ((size_t)NE*NF*ND)

typedef short bf16x8 __attribute__((ext_vector_type(8)));
typedef float f32x4 __attribute__((ext_vector_type(4)));

__device__ __forceinline__ unsigned short f2bf(float f) {
  unsigned u = __float_as_uint(f);
  unsigned r = (u + 0x7FFFu + ((u >> 16) & 1u)) >> 16;
  return (unsigned short)r;
}
__device__ __forceinline__ float bf2f(unsigned short s) {
  return __uint_as_float(((unsigned)s) << 16);
}

__device__ __forceinline__ void async16(unsigned short* lds, const unsigned short* g) {
  __builtin_amdgcn_global_load_lds(
      (const __attribute__((address_space(1))) unsigned int*)g,
      (__attribute__((address_space(3))) unsigned int*)lds, 16, 0, 0);
}

// ---------------- convert fp32 -> bf16 (vectorized) ----------------
__global__ void cvt_bf16(const float* __restrict__ src,
                         unsigned short* __restrict__ dst, int n4) {
  int i = blockIdx.x * blockDim.x + threadIdx.x;
  int stride = gridDim.x * blockDim.x;
  for (; i < n4; i += stride) {
    float4 v = ((const float4*)src)[i];
    ushort4 o;
    o.x = f2bf(v.x); o.y = f2bf(v.y); o.z = f2bf(v.z); o.w = f2bf(v.w);
    ((ushort4*)dst)[i] = o;
  }
}

// ---------------- transpose w2 (E,F,D) fp32 -> w2t (E,D,F) bf16 ----------------
__global__ void transpose_w2(const float* __restrict__ w2,
                             unsigned short* __restrict__ w2t) {
  __shared__ float tile[32][33];
  int e = blockIdx.z;
  int d0 = blockIdx.x * 32, f0 = blockIdx.y * 32;
  int tx = threadIdx.x, ty = threadIdx.y;
  const float* src = w2 + (size_t)e * NF * ND;
  unsigned short* dst = w2t + (size_t)e * ND * NF;
#pragma unroll
  for (int i = ty; i < 32; i += 8)
    tile[i][tx] = src[(size_t)(f0 + i) * ND + d0 + tx];
  __syncthreads();
#pragma unroll
  for (int i = ty; i < 32; i += 8)
    dst[(size_t)(d0 + i) * NF + f0 + tx] = f2bf(tile[tx][i]);
}

// ---------------- router: logits, softmax, top-2, lists ----------------
__global__ void router_kernel(const float* __restrict__ hs,
                              const float* __restrict__ rk,
                              float* __restrict__ wout,   // [NTOK][NE] softmax probs
                              float* __restrict__ tw,     // [NTOK][2] normalized top weights
                              int* __restrict__ counts,   // [NE]
                              int* __restrict__ list) {   // [NE][NTOK] entries (t<<1)|slot
  int t = blockIdx.x;
  int lane = threadIdx.x;
  const float* row = hs + (size_t)t * ND;
  float acc[NE];
#pragma unroll
  for (int e = 0; e < NE; ++e) acc[e] = 0.f;
  for (int d = lane; d < ND; d += 64) {
    float x = row[d];
    const float* r = rk + (size_t)d * NE;
#pragma unroll
    for (int e = 0; e < NE; ++e) acc[e] += x * r[e];
  }
#pragma unroll
  for (int off = 32; off > 0; off >>= 1) {
#pragma unroll
    for (int e = 0; e < NE; ++e) acc[e] += __shfl_xor(acc[e], off, 64);
  }
  if (lane == 0) {
    float mx = acc[0]; int i0 = 0;
#pragma unroll
    for (int e = 1; e < NE; ++e) if (acc[e] > mx) { mx = acc[e]; i0 = e; }
    float m2 = -3.4e38f; int i1 = 0;
#pragma unroll
    for (int e = 0; e < NE; ++e) if (e != i0 && acc[e] > m2) { m2 = acc[e]; i1 = e; }
    float p[NE]; float den = 0.f;
#pragma unroll
    for (int e = 0; e < NE; ++e) { p[e] = expf(acc[e] - mx); den += p[e]; }
    float inv = 1.f / den;
#pragma unroll
    for (int e = 0; e < NE; ++e) { p[e] *= inv; wout[t * NE + e] = p[e]; }
    float w0 = p[i0], w1 = p[i1];
    float s = 1.f / (w0 + w1);
    tw[t * 2 + 0] = w0 * s;
    tw[t * 2 + 1] = w1 * s;
    int pos0 = atomicAdd(&counts[i0], 1);
    list[i0 * NTOK + pos0] = (t << 1);
    int pos1 = atomicAdd(&counts[i1], 1);
    list[i1 * NTOK + pos1] = (t << 1) | 1;
  }
}

// ---------------- gathered NT GEMM with MFMA + LDS double-buffer ----------------
// block = 256 threads = 4 waves (2x2), block tile 128x128, wave tile 64x64, BK=32
// A rows gathered via per-expert list. C rows addressed by (slot,token).
// mode 0: store acc as bf16 to Cb (x1)
// mode 1: h = silu(X1)*acc -> bf16 Cb
// mode 2: store acc fp32 to Cf (y)
__global__ __launch_bounds__(256) void gemm_nt(
    const int* __restrict__ counts, const int* __restrict__ list,
    const unsigned short* __restrict__ A, int lda, int aRowMode,
    const unsigned short* __restrict__ B, long bStrideE, int ldb,
    int nTilesN, int kTiles, int mode,
    unsigned short* __restrict__ Cb,
    const unsigned short* __restrict__ X1,
    float* __restrict__ Cf, int ldc) {
  int bid = blockIdx.x;
  int e = bid / (32 * nTilesN);
  int rem = bid - e * 32 * nTilesN;
  int mt = rem / nTilesN;
  int nt = rem - mt * nTilesN;
  int cnt = counts[e];
  if (mt * 128 >= cnt) return;

  // LDS: [buf][op][128 rows][32 elems] bf16 -> 2*2*8KB = 32 KB
  __shared__ unsigned short lds[2][2][128 * 32];

  int tid = threadIdx.x;
  int wid = tid >> 6, lane = tid & 63;
  int wr = wid >> 1, wc = wid & 1;
  const int* mylist = list + e * NTOK;
  int l15 = lane & 15, l4 = lane >> 4;

  // ---- staging source pointers (per-lane global, linear LDS dest) ----
  // thread t covers LDS bytes t*16 within each 4KB issue; row = t/4, slot = t&3
  int srow = wid * 16 + (lane >> 2);   // row within 64-row issue half
  int slotOff = (lane & 3) * 8;        // element offset within row
  const unsigned short* aS[2];
#pragma unroll
  for (int i = 0; i < 2; ++i) {
    int r = mt * 128 + i * 64 + srow;
    if (r >= cnt) r = cnt - 1;
    int entry = mylist[r];
    int tok = entry >> 1, slot = entry & 1;
    long arow = aRowMode ? ((long)slot * NTOK + tok) : (long)tok;
    aS[i] = A + arow * lda + slotOff;
  }
  const unsigned short* bbase = B + (long)e * bStrideE;
  const unsigned short* bS[2];
#pragma unroll
  for (int i = 0; i < 2; ++i) {
    int c = nt * 128 + i * 64 + srow;
    bS[i] = bbase + (long)c * ldb + slotOff;
  }

  // ---- fragment read offsets (ushort units), row stride 32 ----
  int aoff = (wr * 64 + l15) * 32 + l4 * 8;
  int boff = (wc * 64 + l15) * 32 + l4 * 8;

  f32x4 acc[4][4];
#pragma unroll
  for (int mi = 0; mi < 4; ++mi)
#pragma unroll
    for (int ni = 0; ni < 4; ++ni) {
      f32x4 z = {0.f, 0.f, 0.f, 0.f};
      acc[mi][ni] = z;
    }

#define STAGE(c, kt) do { \
    int ko = (kt) * 32; \
    async16(&lds[c][0][0 * 2048 + wid * 512], aS[0] + ko); \
    async16(&lds[c][0][1 * 2048 + wid * 512], aS[1] + ko); \
    async16(&lds[c][1][0 * 2048 + wid * 512], bS[0] + ko); \
    async16(&lds[c][1][1 * 2048 + wid * 512], bS[1] + ko); \
  } while (0)

  STAGE(0, 0);
  int cur = 0;
  for (int kt = 0; kt < kTiles; ++kt) {
    __syncthreads();                       // stage(cur) complete, prev compute done
    if (kt + 1 < kTiles) STAGE(cur ^ 1, kt + 1);
    const unsigned short* la = &lds[cur][0][0];
    const unsigned short* lb = &lds[cur][1][0];
    bf16x8 af[4], bfr[4];
#pragma unroll
    for (int mi = 0; mi < 4; ++mi)
      af[mi] = *reinterpret_cast<const bf16x8*>(la + aoff + mi * 512);
#pragma unroll
    for (int ni = 0; ni < 4; ++ni)
      bfr[ni] = *reinterpret_cast<const bf16x8*>(lb + boff + ni * 512);
#pragma unroll
    for (int mi = 0; mi < 4; ++mi)
#pragma unroll
      for (int ni = 0; ni < 4; ++ni)
        acc[mi][ni] = __builtin_amdgcn_mfma_f32_16x16x32_bf16(
            af[mi], bfr[ni], acc[mi][ni], 0, 0, 0);
    cur ^= 1;
  }
#undef STAGE

  // epilogue: C/D layout col=lane&15, row=(lane>>4)*4+j
  int rowbase = mt * 128 + wr * 64;
  int colbase = nt * 128 + wc * 64;
#pragma unroll
  for (int mi = 0; mi < 4; ++mi) {
#pragma unroll
    for (int j = 0; j < 4; ++j) {
      int r = rowbase + mi * 16 + l4 * 4 + j;
      if (r >= cnt) continue;
      int entry = mylist[r];
      int tok = entry >> 1, slot = entry & 1;
      long crow = (long)slot * NTOK + tok;
      if (mode == 0) {
#pragma unroll
        for (int ni = 0; ni < 4; ++ni) {
          int c = colbase + ni * 16 + l15;
          Cb[crow * ldc + c] = f2bf(acc[mi][ni][j]);
        }
      } else if (mode == 1) {
#pragma unroll
        for (int ni = 0; ni < 4; ++ni) {
          int c = colbase + ni * 16 + l15;
          float x1 = bf2f(X1[crow * ldc + c]);
          float x2 = acc[mi][ni][j];
          float h = (x1 / (1.f + expf(-x1))) * x2;
          Cb[crow * ldc + c] = f2bf(h);
        }
      } else {
#pragma unroll
        for (int ni = 0; ni < 4; ++ni) {
          int c = colbase + ni * 16 + l15;
          Cf[crow * ldc + c] = acc[mi][ni][j];
        }
      }
    }
  }
}

// ---------------- combine: out = tw0*y0 + tw1*y1 ----------------
__global__ void combine_kernel(const float* __restrict__ ybuf,
                               const float* __restrict__ tw,
                               float* __restrict__ out) {
  int i = blockIdx.x * blockDim.x + threadIdx.x;
  const int total = NTOK * ND / 4;
  int stride = gridDim.x * blockDim.x;
  for (; i < total; i += stride) {
    int t = i >> 8;  // ND/4 = 256 quads per token
    float w0 = tw[t * 2], w1 = tw[t * 2 + 1];
    float4 y0 = ((const float4*)ybuf)[i];
    float4 y1 = ((const float4*)(ybuf + (size_t)NTOK * ND))[i];
    float4 o;
    o.x = w0 * y0.x + w1 * y1.x;
    o.y = w0 * y0.y + w1 * y1.y;
    o.z = w0 * y0.z + w1 * y1.z;
    o.w = w0 * y0.w + w1 * y1.w;
    ((float4*)out)[i] = o;
  }
}

// ---------------- workspace layout (bytes) ----------------
// counts:   0        (256)
// list:     256      (8*4096*4 = 131072)        end 131328
// tw:       131328   (4096*2*4 = 32768)         end 164096
// hsb:      164096   (4096*1024*2 = 8388608)    end 8552704
// w1b:      8552704  (33554432)                 end 42107136
// v1b:      42107136 (33554432)                 end 75661568
// w2t:      75661568 (33554432)                 end 109216000
// x1buf:    109216000 (2*4096*2048*2 = 33554432) end 142770432
// hbuf:     142770432 (33554432)                end 176324864
// ybuf:     176324864 (2*4096*1024*4 = 33554432) end 209879296

extern "C" void kernel_launch(void* const* d_in, const int* in_sizes, int n_in,
                              void* d_out, int out_size, void* d_ws, size_t ws_size,
                              hipStream_t stream) {
  const float* hs = (const float*)d_in[0];
  const float* rk = (const float*)d_in[1];
  const float* w1 = (const float*)d_in[2];
  const float* v1 = (const float*)d_in[3];
  const float* w2 = (const float*)d_in[4];
  float* out = (float*)d_out;
  float* wout = out + (size_t)NTOK * ND;  // weights output [NTOK][NE]

  char* ws = (char*)d_ws;
  int* counts = (int*)(ws + 0);
  int* list = (int*)(ws + 256);
  float* tw = (float*)(ws + 131328);
  unsigned short* hsb = (unsigned short*)(ws + 164096);
  unsigned short* w1b = (unsigned short*)(ws + 8552704);
  unsigned short* v1b = (unsigned short*)(ws + 42107136);
  unsigned short* w2t = (unsigned short*)(ws + 75661568);
  unsigned short* x1buf = (unsigned short*)(ws + 109216000);
  unsigned short* hbuf = (unsigned short*)(ws + 142770432);
  float* ybuf = (float*)(ws + 176324864);

  hipMemsetAsync(counts, 0, 256, stream);

  // fp32 -> bf16 conversions
  cvt_bf16<<<2048, 256, 0, stream>>>(hs, hsb, NTOK * ND / 4);
  cvt_bf16<<<4096, 256, 0, stream>>>(w1, w1b, (int)(EFD / 4));
  cvt_bf16<<<4096, 256, 0, stream>>>(v1, v1b, (int)(EFD / 4));
  transpose_w2<<<dim3(ND / 32, NF / 32, NE), dim3(32, 8), 0, stream>>>(w2, w2t);

  router_kernel<<<NTOK, 64, 0, stream>>>(hs, rk, wout, tw, counts, list);

  // pass1: x1 = X @ w1^T   (K=1024, N=2048)
  gemm_nt<<<NE * 32 * 16, 256, 0, stream>>>(
      counts, list, hsb, ND, 0, w1b, (long)NF * ND, ND,
      16, ND / 32, 0, x1buf, nullptr, nullptr, NF);
  // pass2: x2 = X @ v1^T, h = silu(x1)*x2
  gemm_nt<<<NE * 32 * 16, 256, 0, stream>>>(
      counts, list, hsb, ND, 0, v1b, (long)NF * ND, ND,
      16, ND / 32, 1, hbuf, x1buf, nullptr, NF);
  // pass3: y = h @ w2t^T   (K=2048, N=1024)
  gemm_nt<<<NE * 32 * 8, 256, 0, stream>>>(
      counts, list, hbuf, NF, 1, w2t, (long)ND * NF, NF,
      8, NF / 32, 2, nullptr, nullptr, ybuf, ND);

  combine_kernel<<<2048, 256, 0, stream>>>(ybuf, tw, out);
}

// Round 3
// 318.904 us; speedup vs baseline: 2.2514x; 1.2651x over previous
//
#include <hip/hip_runtime.h>
#include <stdint.h>
#include <math.h>

// Problem constants (DBRX FFN): B=2 S=2048 D=1024 E=8 F=2048 K=2
#define NB 2
#define NS 2048
#define ND 1024
#define NE 8
#define NF 2048
#define NTOK (NB*NS)          // 4096 tokens
#define EFD ((size_t)NE*NF*ND)

typedef short bf16x8 __attribute__((ext_vector_type(8)));
typedef float f32x4 __attribute__((ext_vector_type(4)));

__device__ __forceinline__ unsigned short f2bf(float f) {
  unsigned u = __float_as_uint(f);
  unsigned r = (u + 0x7FFFu + ((u >> 16) & 1u)) >> 16;
  return (unsigned short)r;
}
__device__ __forceinline__ float bf2f(unsigned short s) {
  return __uint_as_float(((unsigned)s) << 16);
}

__device__ __forceinline__ void async16(unsigned short* lds, const unsigned short* g) {
  __builtin_amdgcn_global_load_lds(
      (const __attribute__((address_space(1))) unsigned int*)g,
      (__attribute__((address_space(3))) unsigned int*)lds, 16, 0, 0);
}

// ---------------- convert fp32 -> bf16 (vectorized) ----------------
__global__ void cvt_bf16(const float* __restrict__ src,
                         unsigned short* __restrict__ dst, int n4) {
  int i = blockIdx.x * blockDim.x + threadIdx.x;
  int stride = gridDim.x * blockDim.x;
  for (; i < n4; i += stride) {
    float4 v = ((const float4*)src)[i];
    ushort4 o;
    o.x = f2bf(v.x); o.y = f2bf(v.y); o.z = f2bf(v.z); o.w = f2bf(v.w);
    ((ushort4*)dst)[i] = o;
  }
}

// ---------------- transpose w2 (E,F,D) fp32 -> w2t (E,D,F) bf16 ----------------
__global__ void transpose_w2(const float* __restrict__ w2,
                             unsigned short* __restrict__ w2t) {
  __shared__ float tile[32][33];
  int e = blockIdx.z;
  int d0 = blockIdx.x * 32, f0 = blockIdx.y * 32;
  int tx = threadIdx.x, ty = threadIdx.y;
  const float* src = w2 + (size_t)e * NF * ND;
  unsigned short* dst = w2t + (size_t)e * ND * NF;
#pragma unroll
  for (int i = ty; i < 32; i += 8)
    tile[i][tx] = src[(size_t)(f0 + i) * ND + d0 + tx];
  __syncthreads();
#pragma unroll
  for (int i = ty; i < 32; i += 8)
    dst[(size_t)(d0 + i) * NF + f0 + tx] = f2bf(tile[tx][i]);
}

// ---------------- router: wave per 16 tokens, 4 lanes per token ----------------
// Also fuses hs fp32->bf16 conversion. No atomics; writes packed choice[t].
__global__ void router_kernel(const float* __restrict__ hs,
                              const float* __restrict__ rk,
                              float* __restrict__ wout,   // [NTOK][NE]
                              float* __restrict__ tw,     // [NTOK][2]
                              int* __restrict__ choice,   // [NTOK] e0 | e1<<4
                              unsigned short* __restrict__ hsb) {
  int lane = threadIdx.x;            // 64
  int tt = lane & 15, part = lane >> 4;
  int t = blockIdx.x * 16 + tt;      // 256 blocks
  const float4* hrow = (const float4*)(hs + (size_t)t * ND) + part * 64;
  ushort4* hb4 = (ushort4*)(hsb + (size_t)t * ND) + part * 64;
  const float4* rk4 = (const float4*)rk + part * 512;  // rk[d][e], d window = part*256
  float acc[NE];
#pragma unroll
  for (int e = 0; e < NE; ++e) acc[e] = 0.f;
#pragma unroll 4
  for (int i = 0; i < 64; ++i) {
    float4 x = hrow[i];
    ushort4 o;
    o.x = f2bf(x.x); o.y = f2bf(x.y); o.z = f2bf(x.z); o.w = f2bf(x.w);
    hb4[i] = o;
    float xs[4] = {x.x, x.y, x.z, x.w};
#pragma unroll
    for (int j = 0; j < 4; ++j) {
      float4 r0 = rk4[i * 8 + j * 2];
      float4 r1 = rk4[i * 8 + j * 2 + 1];
      acc[0] += xs[j] * r0.x; acc[1] += xs[j] * r0.y;
      acc[2] += xs[j] * r0.z; acc[3] += xs[j] * r0.w;
      acc[4] += xs[j] * r1.x; acc[5] += xs[j] * r1.y;
      acc[6] += xs[j] * r1.z; acc[7] += xs[j] * r1.w;
    }
  }
#pragma unroll
  for (int e = 0; e < NE; ++e) {
    acc[e] += __shfl_xor(acc[e], 16, 64);
    acc[e] += __shfl_xor(acc[e], 32, 64);
  }
  if (part == 0) {
    float mx = acc[0]; int i0 = 0;
#pragma unroll
    for (int e = 1; e < NE; ++e) if (acc[e] > mx) { mx = acc[e]; i0 = e; }
    float m2 = -3.4e38f; int i1 = 0;
#pragma unroll
    for (int e = 0; e < NE; ++e) if (e != i0 && acc[e] > m2) { m2 = acc[e]; i1 = e; }
    float p[NE]; float den = 0.f;
#pragma unroll
    for (int e = 0; e < NE; ++e) { p[e] = expf(acc[e] - mx); den += p[e]; }
    float inv = 1.f / den;
#pragma unroll
    for (int e = 0; e < NE; ++e) { p[e] *= inv; wout[t * NE + e] = p[e]; }
    float w0 = p[i0], w1 = p[i1];
    float s = 1.f / (w0 + w1);
    tw[t * 2 + 0] = w0 * s;
    tw[t * 2 + 1] = w1 * s;
    choice[t] = i0 | (i1 << 4);
  }
}

// ---------------- build per-expert token lists (single block, LDS atomics) ----
__global__ void build_lists(const int* __restrict__ choice,
                            int* __restrict__ counts,
                            int* __restrict__ list) {
  __shared__ int lcnt[NE];
  int tid = threadIdx.x;  // 1024
  if (tid < NE) lcnt[tid] = 0;
  __syncthreads();
  int4 c4 = ((const int4*)choice)[tid];
  int cs[4] = {c4.x, c4.y, c4.z, c4.w};
#pragma unroll
  for (int j = 0; j < 4; ++j) {
    int t = tid * 4 + j;
    int e0 = cs[j] & 15, e1 = (cs[j] >> 4) & 15;
    int p0 = atomicAdd(&lcnt[e0], 1);
    list[e0 * NTOK + p0] = t << 1;
    int p1 = atomicAdd(&lcnt[e1], 1);
    list[e1 * NTOK + p1] = (t << 1) | 1;
  }
  __syncthreads();
  if (tid < NE) counts[tid] = lcnt[tid];
}

// ---------------- fused pass1+pass2: x1=X@w1^T, x2=X@v1^T, h=silu(x1)*x2 -----
// block 256 = 4 waves (2x2); block tile M=128, N=64 (per matrix); BK=32
__global__ __launch_bounds__(256) void gemm_fused12(
    const int* __restrict__ counts, const int* __restrict__ list,
    const unsigned short* __restrict__ A,    // hsb [NTOK][ND]
    const unsigned short* __restrict__ B1,   // w1b [E][F][D]
    const unsigned short* __restrict__ B2,   // v1b
    unsigned short* __restrict__ H) {        // hbuf [2*NTOK][NF]
  int bid = blockIdx.x;
  int e = bid >> 10;               // / (32 mt * 32 nt)
  int rem = bid & 1023;
  int mt = rem >> 5, nt = rem & 31;
  int cnt = counts[e];
  if (mt * 128 >= cnt) return;

  __shared__ unsigned short ldsA[2][128 * 32];   // 16 KB
  __shared__ unsigned short ldsB[2][2][64 * 32]; // 16 KB

  int tid = threadIdx.x;
  int wid = tid >> 6, lane = tid & 63;
  int wr = wid >> 1, wc = wid & 1;
  const int* mylist = list + e * NTOK;
  int l15 = lane & 15, l4 = lane >> 4;

  int srow = wid * 16 + (lane >> 2);   // row within 64-row issue
  int slotOff = (lane & 3) * 8;
  const unsigned short* aS[2];
#pragma unroll
  for (int i = 0; i < 2; ++i) {
    int r = mt * 128 + i * 64 + srow;
    if (r >= cnt) r = cnt - 1;
    int entry = mylist[r];
    int tok = entry >> 1;
    aS[i] = A + (size_t)tok * ND + slotOff;
  }
  const unsigned short* b1S =
      B1 + (size_t)e * NF * ND + (size_t)(nt * 64 + srow) * ND + slotOff;
  const unsigned short* b2S =
      B2 + (size_t)e * NF * ND + (size_t)(nt * 64 + srow) * ND + slotOff;

  int aoff = (wr * 64 + l15) * 32 + l4 * 8;
  int boff = (wc * 32 + l15) * 32 + l4 * 8;

  f32x4 acc1[4][2], acc2[4][2];
#pragma unroll
  for (int mi = 0; mi < 4; ++mi)
#pragma unroll
    for (int ni = 0; ni < 2; ++ni) {
      f32x4 z = {0.f, 0.f, 0.f, 0.f};
      acc1[mi][ni] = z; acc2[mi][ni] = z;
    }

#define STAGE(c, kt) do { \
    int ko = (kt) * 32; \
    async16(&ldsA[c][0 * 2048 + wid * 512], aS[0] + ko); \
    async16(&ldsA[c][1 * 2048 + wid * 512], aS[1] + ko); \
    async16(&ldsB[c][0][wid * 512], b1S + ko); \
    async16(&ldsB[c][1][wid * 512], b2S + ko); \
  } while (0)

  STAGE(0, 0);
  int cur = 0;
  for (int kt = 0; kt < ND / 32; ++kt) {
    __syncthreads();
    if (kt + 1 < ND / 32) STAGE(cur ^ 1, kt + 1);
    const unsigned short* la = &ldsA[cur][0];
    const unsigned short* lb1 = &ldsB[cur][0][0];
    const unsigned short* lb2 = &ldsB[cur][1][0];
    bf16x8 af[4], b1f[2], b2f[2];
#pragma unroll
    for (int mi = 0; mi < 4; ++mi)
      af[mi] = *reinterpret_cast<const bf16x8*>(la + aoff + mi * 512);
#pragma unroll
    for (int ni = 0; ni < 2; ++ni) {
      b1f[ni] = *reinterpret_cast<const bf16x8*>(lb1 + boff + ni * 512);
      b2f[ni] = *reinterpret_cast<const bf16x8*>(lb2 + boff + ni * 512);
    }
#pragma unroll
    for (int mi = 0; mi < 4; ++mi)
#pragma unroll
      for (int ni = 0; ni < 2; ++ni) {
        acc1[mi][ni] = __builtin_amdgcn_mfma_f32_16x16x32_bf16(
            af[mi], b1f[ni], acc1[mi][ni], 0, 0, 0);
        acc2[mi][ni] = __builtin_amdgcn_mfma_f32_16x16x32_bf16(
            af[mi], b2f[ni], acc2[mi][ni], 0, 0, 0);
      }
    cur ^= 1;
  }
#undef STAGE

  int rowbase = mt * 128 + wr * 64;
  int colbase = nt * 64 + wc * 32;
#pragma unroll
  for (int mi = 0; mi < 4; ++mi) {
#pragma unroll
    for (int j = 0; j < 4; ++j) {
      int r = rowbase + mi * 16 + l4 * 4 + j;
      if (r >= cnt) continue;
      int entry = mylist[r];
      int tok = entry >> 1, slot = entry & 1;
      long crow = (long)slot * NTOK + tok;
#pragma unroll
      for (int ni = 0; ni < 2; ++ni) {
        int c = colbase + ni * 16 + l15;
        float x1 = acc1[mi][ni][j];
        float x2 = acc2[mi][ni][j];
        float h = (x1 / (1.f + expf(-x1))) * x2;
        H[crow * NF + c] = f2bf(h);
      }
    }
  }
}

// ---------------- pass3 gathered NT GEMM (y = h @ w2t^T), fp32 out ----------
__global__ __launch_bounds__(256) void gemm_nt(
    const int* __restrict__ counts, const int* __restrict__ list,
    const unsigned short* __restrict__ A, int lda, int aRowMode,
    const unsigned short* __restrict__ B, long bStrideE, int ldb,
    int nTilesN, int kTiles,
    float* __restrict__ Cf, int ldc) {
  int bid = blockIdx.x;
  int e = bid / (32 * nTilesN);
  int rem = bid - e * 32 * nTilesN;
  int mt = rem / nTilesN;
  int nt = rem - mt * nTilesN;
  int cnt = counts[e];
  if (mt * 128 >= cnt) return;

  __shared__ unsigned short lds[2][2][128 * 32];

  int tid = threadIdx.x;
  int wid = tid >> 6, lane = tid & 63;
  int wr = wid >> 1, wc = wid & 1;
  const int* mylist = list + e * NTOK;
  int l15 = lane & 15, l4 = lane >> 4;

  int srow = wid * 16 + (lane >> 2);
  int slotOff = (lane & 3) * 8;
  const unsigned short* aS[2];
#pragma unroll
  for (int i = 0; i < 2; ++i) {
    int r = mt * 128 + i * 64 + srow;
    if (r >= cnt) r = cnt - 1;
    int entry = mylist[r];
    int tok = entry >> 1, slot = entry & 1;
    long arow = aRowMode ? ((long)slot * NTOK + tok) : (long)tok;
    aS[i] = A + arow * lda + slotOff;
  }
  const unsigned short* bbase = B + (long)e * bStrideE;
  const unsigned short* bS[2];
#pragma unroll
  for (int i = 0; i < 2; ++i) {
    int c = nt * 128 + i * 64 + srow;
    bS[i] = bbase + (long)c * ldb + slotOff;
  }

  int aoff = (wr * 64 + l15) * 32 + l4 * 8;
  int boff = (wc * 64 + l15) * 32 + l4 * 8;

  f32x4 acc[4][4];
#pragma unroll
  for (int mi = 0; mi < 4; ++mi)
#pragma unroll
    for (int ni = 0; ni < 4; ++ni) {
      f32x4 z = {0.f, 0.f, 0.f, 0.f};
      acc[mi][ni] = z;
    }

#define STAGE(c, kt) do { \
    int ko = (kt) * 32; \
    async16(&lds[c][0][0 * 2048 + wid * 512], aS[0] + ko); \
    async16(&lds[c][0][1 * 2048 + wid * 512], aS[1] + ko); \
    async16(&lds[c][1][0 * 2048 + wid * 512], bS[0] + ko); \
    async16(&lds[c][1][1 * 2048 + wid * 512], bS[1] + ko); \
  } while (0)

  STAGE(0, 0);
  int cur = 0;
  for (int kt = 0; kt < kTiles; ++kt) {
    __syncthreads();
    if (kt + 1 < kTiles) STAGE(cur ^ 1, kt + 1);
    const unsigned short* la = &lds[cur][0][0];
    const unsigned short* lb = &lds[cur][1][0];
    bf16x8 af[4], bfr[4];
#pragma unroll
    for (int mi = 0; mi < 4; ++mi)
      af[mi] = *reinterpret_cast<const bf16x8*>(la + aoff + mi * 512);
#pragma unroll
    for (int ni = 0; ni < 4; ++ni)
      bfr[ni] = *reinterpret_cast<const bf16x8*>(lb + boff + ni * 512);
#pragma unroll
    for (int mi = 0; mi < 4; ++mi)
#pragma unroll
      for (int ni = 0; ni < 4; ++ni)
        acc[mi][ni] = __builtin_amdgcn_mfma_f32_16x16x32_bf16(
            af[mi], bfr[ni], acc[mi][ni], 0, 0, 0);
    cur ^= 1;
  }
#undef STAGE

  int rowbase = mt * 128 + wr * 64;
  int colbase = nt * 128 + wc * 64;
#pragma unroll
  for (int mi = 0; mi < 4; ++mi) {
#pragma unroll
    for (int j = 0; j < 4; ++j) {
      int r = rowbase + mi * 16 + l4 * 4 + j;
      if (r >= cnt) continue;
      int entry = mylist[r];
      int tok = entry >> 1, slot = entry & 1;
      long crow = (long)slot * NTOK + tok;
#pragma unroll
      for (int ni = 0; ni < 4; ++ni) {
        int c = colbase + ni * 16 + l15;
        Cf[crow * ldc + c] = acc[mi][ni][j];
      }
    }
  }
}

// ---------------- combine: out = tw0*y0 + tw1*y1 ----------------
__global__ void combine_kernel(const float* __restrict__ ybuf,
                               const float* __restrict__ tw,
                               float* __restrict__ out) {
  int i = blockIdx.x * blockDim.x + threadIdx.x;
  const int total = NTOK * ND / 4;
  int stride = gridDim.x * blockDim.x;
  for (; i < total; i += stride) {
    int t = i >> 8;  // ND/4 = 256 quads per token
    float w0 = tw[t * 2], w1 = tw[t * 2 + 1];
    float4 y0 = ((const float4*)ybuf)[i];
    float4 y1 = ((const float4*)(ybuf + (size_t)NTOK * ND))[i];
    float4 o;
    o.x = w0 * y0.x + w1 * y1.x;
    o.y = w0 * y0.y + w1 * y1.y;
    o.z = w0 * y0.z + w1 * y1.z;
    o.w = w0 * y0.w + w1 * y1.w;
    ((float4*)out)[i] = o;
  }
}

// ---------------- workspace layout (bytes) ----------------
// counts:   0         (256)
// list:     256       (8*4096*4 = 131072)        end 131328
// tw:       131328    (32768)                    end 164096
// choice:   164096    (16384)                    end 180480
// hsb:      180480    (8388608)                  end 8569088
// w1b:      8569088   (33554432)                 end 42123520
// v1b:      42123520  (33554432)                 end 75677952
// w2t:      75677952  (33554432)                 end 109232384
// hbuf:     109232384 (33554432)                 end 142786816
// ybuf:     142786816 (33554432)                 end 176341248

extern "C" void kernel_launch(void* const* d_in, const int* in_sizes, int n_in,
                              void* d_out, int out_size, void* d_ws, size_t ws_size,
                              hipStream_t stream) {
  const float* hs = (const float*)d_in[0];
  const float* rk = (const float*)d_in[1];
  const float* w1 = (const float*)d_in[2];
  const float* v1 = (const float*)d_in[3];
  const float* w2 = (const float*)d_in[4];
  float* out = (float*)d_out;
  float* wout = out + (size_t)NTOK * ND;  // weights output [NTOK][NE]

  char* ws = (char*)d_ws;
  int* counts = (int*)(ws + 0);
  int* list = (int*)(ws + 256);
  float* tw = (float*)(ws + 131328);
  int* choice = (int*)(ws + 164096);
  unsigned short* hsb = (unsigned short*)(ws + 180480);
  unsigned short* w1b = (unsigned short*)(ws + 8569088);
  unsigned short* v1b = (unsigned short*)(ws + 42123520);
  unsigned short* w2t = (unsigned short*)(ws + 75677952);
  unsigned short* hbuf = (unsigned short*)(ws + 109232384);
  float* ybuf = (float*)(ws + 142786816);

  // router (also converts hs -> bf16), then list construction
  router_kernel<<<256, 64, 0, stream>>>(hs, rk, wout, tw, choice, hsb);
  build_lists<<<1, 1024, 0, stream>>>(choice, counts, list);

  // weight conversions
  cvt_bf16<<<4096, 256, 0, stream>>>(w1, w1b, (int)(EFD / 4));
  cvt_bf16<<<4096, 256, 0, stream>>>(v1, v1b, (int)(EFD / 4));
  transpose_w2<<<dim3(ND / 32, NF / 32, NE), dim3(32, 8), 0, stream>>>(w2, w2t);

  // fused pass1+2: h = silu(X@w1^T) * (X@v1^T)
  gemm_fused12<<<NE * 32 * 32, 256, 0, stream>>>(counts, list, hsb, w1b, v1b, hbuf);

  // pass3: y = h @ w2t^T   (K=2048, N=1024)
  gemm_nt<<<NE * 32 * 8, 256, 0, stream>>>(
      counts, list, hbuf, NF, 1, w2t, (long)ND * NF, NF,
      8, NF / 32, ybuf, ND);

  combine_kernel<<<2048, 256, 0, stream>>>(ybuf, tw, out);
}

// Round 4
// 300.493 us; speedup vs baseline: 2.3894x; 1.0613x over previous
//
#include <hip/hip_runtime.h>
#include <stdint.h>
#include <math.h>

// Problem constants (DBRX FFN): B=2 S=2048 D=1024 E=8 F=2048 K=2
#define NB 2
#define NS 2048
#define ND 1024
#define NE 8
#define NF 2048
#define NTOK (NB*NS)          // 4096 tokens
#define EFD ((size_t)NE*NF*ND)

typedef short bf16x8 __attribute__((ext_vector_type(8)));
typedef float f32x4 __attribute__((ext_vector_type(4)));

__device__ __forceinline__ unsigned short f2bf(float f) {
  unsigned u = __float_as_uint(f);
  unsigned r = (u + 0x7FFFu + ((u >> 16) & 1u)) >> 16;
  return (unsigned short)r;
}
__device__ __forceinline__ float bf2f(unsigned short s) {
  return __uint_as_float(((unsigned)s) << 16);
}

__device__ __forceinline__ void async16(unsigned short* lds, const unsigned short* g) {
  __builtin_amdgcn_global_load_lds(
      (const __attribute__((address_space(1))) unsigned int*)g,
      (__attribute__((address_space(3))) unsigned int*)lds, 16, 0, 0);
}

#define VMCNT(n) asm volatile("s_waitcnt vmcnt(" #n ")" ::: "memory")
#define LGKM0    asm volatile("s_waitcnt lgkmcnt(0)" ::: "memory")
#define SBAR     __builtin_amdgcn_s_barrier()
#define SCHED0   __builtin_amdgcn_sched_barrier(0)

// ---------------- convert fp32 -> bf16 (vectorized) ----------------
__global__ void cvt_bf16(const float* __restrict__ src,
                         unsigned short* __restrict__ dst, int n4) {
  int i = blockIdx.x * blockDim.x + threadIdx.x;
  int stride = gridDim.x * blockDim.x;
  for (; i < n4; i += stride) {
    float4 v = ((const float4*)src)[i];
    ushort4 o;
    o.x = f2bf(v.x); o.y = f2bf(v.y); o.z = f2bf(v.z); o.w = f2bf(v.w);
    ((ushort4*)dst)[i] = o;
  }
}

// ---------------- transpose w2 (E,F,D) fp32 -> w2t (E,D,F) bf16 ----------------
__global__ void transpose_w2(const float* __restrict__ w2,
                             unsigned short* __restrict__ w2t) {
  __shared__ float tile[32][33];
  int e = blockIdx.z;
  int d0 = blockIdx.x * 32, f0 = blockIdx.y * 32;
  int tx = threadIdx.x, ty = threadIdx.y;
  const float* src = w2 + (size_t)e * NF * ND;
  unsigned short* dst = w2t + (size_t)e * ND * NF;
#pragma unroll
  for (int i = ty; i < 32; i += 8)
    tile[i][tx] = src[(size_t)(f0 + i) * ND + d0 + tx];
  __syncthreads();
#pragma unroll
  for (int i = ty; i < 32; i += 8)
    dst[(size_t)(d0 + i) * NF + f0 + tx] = f2bf(tile[tx][i]);
}

// ---------------- router: wave per 16 tokens, 4 lanes per token ----------------
__global__ void router_kernel(const float* __restrict__ hs,
                              const float* __restrict__ rk,
                              float* __restrict__ wout,   // [NTOK][NE]
                              float* __restrict__ tw,     // [NTOK][2]
                              int* __restrict__ choice,   // [NTOK] e0 | e1<<4
                              unsigned short* __restrict__ hsb) {
  int lane = threadIdx.x;            // 64
  int tt = lane & 15, part = lane >> 4;
  int t = blockIdx.x * 16 + tt;      // 256 blocks
  const float4* hrow = (const float4*)(hs + (size_t)t * ND) + part * 64;
  ushort4* hb4 = (ushort4*)(hsb + (size_t)t * ND) + part * 64;
  const float4* rk4 = (const float4*)rk + part * 512;
  float acc[NE];
#pragma unroll
  for (int e = 0; e < NE; ++e) acc[e] = 0.f;
#pragma unroll 4
  for (int i = 0; i < 64; ++i) {
    float4 x = hrow[i];
    ushort4 o;
    o.x = f2bf(x.x); o.y = f2bf(x.y); o.z = f2bf(x.z); o.w = f2bf(x.w);
    hb4[i] = o;
    float xs[4] = {x.x, x.y, x.z, x.w};
#pragma unroll
    for (int j = 0; j < 4; ++j) {
      float4 r0 = rk4[i * 8 + j * 2];
      float4 r1 = rk4[i * 8 + j * 2 + 1];
      acc[0] += xs[j] * r0.x; acc[1] += xs[j] * r0.y;
      acc[2] += xs[j] * r0.z; acc[3] += xs[j] * r0.w;
      acc[4] += xs[j] * r1.x; acc[5] += xs[j] * r1.y;
      acc[6] += xs[j] * r1.z; acc[7] += xs[j] * r1.w;
    }
  }
#pragma unroll
  for (int e = 0; e < NE; ++e) {
    acc[e] += __shfl_xor(acc[e], 16, 64);
    acc[e] += __shfl_xor(acc[e], 32, 64);
  }
  if (part == 0) {
    float mx = acc[0]; int i0 = 0;
#pragma unroll
    for (int e = 1; e < NE; ++e) if (acc[e] > mx) { mx = acc[e]; i0 = e; }
    float m2 = -3.4e38f; int i1 = 0;
#pragma unroll
    for (int e = 0; e < NE; ++e) if (e != i0 && acc[e] > m2) { m2 = acc[e]; i1 = e; }
    float p[NE]; float den = 0.f;
#pragma unroll
    for (int e = 0; e < NE; ++e) { p[e] = expf(acc[e] - mx); den += p[e]; }
    float inv = 1.f / den;
#pragma unroll
    for (int e = 0; e < NE; ++e) { p[e] *= inv; wout[t * NE + e] = p[e]; }
    float w0 = p[i0], w1 = p[i1];
    float s = 1.f / (w0 + w1);
    tw[t * 2 + 0] = w0 * s;
    tw[t * 2 + 1] = w1 * s;
    choice[t] = i0 | (i1 << 4);
  }
}

// ---------------- build per-expert token lists (single block, LDS atomics) ----
__global__ void build_lists(const int* __restrict__ choice,
                            int* __restrict__ counts,
                            int* __restrict__ list) {
  __shared__ int lcnt[NE];
  int tid = threadIdx.x;  // 1024
  if (tid < NE) lcnt[tid] = 0;
  __syncthreads();
  int4 c4 = ((const int4*)choice)[tid];
  int cs[4] = {c4.x, c4.y, c4.z, c4.w};
#pragma unroll
  for (int j = 0; j < 4; ++j) {
    int t = tid * 4 + j;
    int e0 = cs[j] & 15, e1 = (cs[j] >> 4) & 15;
    int p0 = atomicAdd(&lcnt[e0], 1);
    list[e0 * NTOK + p0] = t << 1;
    int p1 = atomicAdd(&lcnt[e1], 1);
    list[e1 * NTOK + p1] = (t << 1) | 1;
  }
  __syncthreads();
  if (tid < NE) counts[tid] = lcnt[tid];
}

// ---------------- pipelined gathered NT GEMM --------------------------------
// 256 threads = 4 waves (2M x 2N). BM=128, BN=64 (per matrix), BK=64.
// Counted-vmcnt stage-ahead-2 pipeline; XOR chunk swizzle (phys = chunk^(row&7))
// applied as inverse-swizzled global source (linear LDS dest, rule #21) and
// swizzled ds_read offsets.
// NMATS=2: B1,B2 -> h = silu(x1)*x2 -> bf16 H.  NMATS=1: B1 -> fp32 Cf.
template <int NMATS, int AROW>
__global__ __launch_bounds__(256, 2) void gemm_pipe(
    const int* __restrict__ counts, const int* __restrict__ list,
    const unsigned short* __restrict__ A, int lda,
    const unsigned short* __restrict__ B1, const unsigned short* __restrict__ B2,
    long bStrideE, int nTiles, int kTiles,
    unsigned short* __restrict__ H,
    float* __restrict__ Cf, int ldc) {
  int bid = blockIdx.x;
  int e = bid / (32 * nTiles);
  int rem = bid - e * 32 * nTiles;
  int mt = rem / nTiles;
  int nt = rem - mt * nTiles;
  int cnt = counts[e];
  if (mt * 128 >= cnt) return;

  __shared__ unsigned short ldsA[2][128 * 64];          // 32 KB
  __shared__ unsigned short ldsB[2][NMATS][64 * 64];    // 16/32 KB

  int tid = threadIdx.x;
  int wid = tid >> 6, lane = tid & 63;
  int wr = wid >> 1, wc = wid & 1;
  int l15 = lane & 15, l4 = lane >> 4;
  const int* mylist = list + e * NTOK;

  // ---- staging source pointers (inverse-swizzled global, linear LDS dest) ----
  int trow = tid >> 3;                 // 0..31 (row within 32-row group)
  int tphys = tid & 7;                 // physical 16B chunk slot
  int co = (tphys ^ (trow & 7)) << 3;  // logical element offset for this slot
  const unsigned short* aS[4];
#pragma unroll
  for (int g = 0; g < 4; ++g) {
    int r = mt * 128 + g * 32 + trow;
    if (r >= cnt) r = cnt - 1;
    int entry = mylist[r];
    int tok = entry >> 1, slot = entry & 1;
    long arow = AROW ? ((long)slot * NTOK + tok) : (long)tok;
    aS[g] = A + arow * lda + co;
  }
  const unsigned short* b1S[2];
  const unsigned short* b2S[2];
#pragma unroll
  for (int g = 0; g < 2; ++g) {
    int fr = nt * 64 + g * 32 + trow;
    b1S[g] = B1 + (long)e * bStrideE + (long)fr * lda + co;
    if constexpr (NMATS == 2)
      b2S[g] = B2 + (long)e * bStrideE + (long)fr * lda + co;
  }

  // ---- swizzled fragment read offsets (bytes) ----
  int msk = (l15 & 7) << 4;
  int rowA[4], rowB[2];
#pragma unroll
  for (int mi = 0; mi < 4; ++mi) rowA[mi] = (wr * 64 + mi * 16 + l15) * 128;
#pragma unroll
  for (int ni = 0; ni < 2; ++ni) rowB[ni] = (wc * 32 + ni * 16 + l15) * 128;
  int cb = l4 * 16;

  f32x4 acc1[4][2], acc2[4][2];
#pragma unroll
  for (int mi = 0; mi < 4; ++mi)
#pragma unroll
    for (int ni = 0; ni < 2; ++ni) {
      f32x4 z = {0.f, 0.f, 0.f, 0.f};
      acc1[mi][ni] = z; acc2[mi][ni] = z;
    }

  auto STAGEP = [&](int c, int kt) {
    int ko = kt * 64;
#pragma unroll
    for (int g = 0; g < 4; ++g)
      async16(&ldsA[c][g * 2048 + wid * 512], aS[g] + ko);
#pragma unroll
    for (int g = 0; g < 2; ++g) {
      async16(&ldsB[c][0][g * 2048 + wid * 512], b1S[g] + ko);
      if constexpr (NMATS == 2)
        async16(&ldsB[c][NMATS - 1][g * 2048 + wid * 512], b2S[g] + ko);
    }
  };

  STAGEP(0, 0);
  STAGEP(1, 1);
  if constexpr (NMATS == 2) VMCNT(8); else VMCNT(6);
  SCHED0;
  SBAR;

  for (int kt = 0; kt < kTiles; ++kt) {
    int cur = kt & 1;
    const char* la  = (const char*)&ldsA[cur][0];
    const char* lb0 = (const char*)&ldsB[cur][0][0];
    const char* lb1 = (const char*)&ldsB[cur][NMATS - 1][0];

    // ---- ks = 0 ----
    bf16x8 a0[4], p0[2], q0[2];
#pragma unroll
    for (int mi = 0; mi < 4; ++mi)
      a0[mi] = *(const bf16x8*)(la + rowA[mi] + (cb ^ msk));
#pragma unroll
    for (int ni = 0; ni < 2; ++ni) {
      p0[ni] = *(const bf16x8*)(lb0 + rowB[ni] + (cb ^ msk));
      if constexpr (NMATS == 2)
        q0[ni] = *(const bf16x8*)(lb1 + rowB[ni] + (cb ^ msk));
    }
    __builtin_amdgcn_s_setprio(1);
#pragma unroll
    for (int mi = 0; mi < 4; ++mi)
#pragma unroll
      for (int ni = 0; ni < 2; ++ni) {
        acc1[mi][ni] = __builtin_amdgcn_mfma_f32_16x16x32_bf16(
            a0[mi], p0[ni], acc1[mi][ni], 0, 0, 0);
        if constexpr (NMATS == 2)
          acc2[mi][ni] = __builtin_amdgcn_mfma_f32_16x16x32_bf16(
              a0[mi], q0[ni], acc2[mi][ni], 0, 0, 0);
      }
    __builtin_amdgcn_s_setprio(0);

    // ---- ks = 1 loads ----
    bf16x8 a1[4], p1[2], q1[2];
    int cb1 = cb + 64;
#pragma unroll
    for (int mi = 0; mi < 4; ++mi)
      a1[mi] = *(const bf16x8*)(la + rowA[mi] + (cb1 ^ msk));
#pragma unroll
    for (int ni = 0; ni < 2; ++ni) {
      p1[ni] = *(const bf16x8*)(lb0 + rowB[ni] + (cb1 ^ msk));
      if constexpr (NMATS == 2)
        q1[ni] = *(const bf16x8*)(lb1 + rowB[ni] + (cb1 ^ msk));
    }
    LGKM0;      // all my reads of buf[cur] complete
    SCHED0;
    SBAR;       // => ALL waves' reads of buf[cur] complete
    if (kt + 2 < kTiles) STAGEP(cur, kt + 2);   // safe to overwrite buf[cur]
    __builtin_amdgcn_s_setprio(1);
#pragma unroll
    for (int mi = 0; mi < 4; ++mi)
#pragma unroll
      for (int ni = 0; ni < 2; ++ni) {
        acc1[mi][ni] = __builtin_amdgcn_mfma_f32_16x16x32_bf16(
            a1[mi], p1[ni], acc1[mi][ni], 0, 0, 0);
        if constexpr (NMATS == 2)
          acc2[mi][ni] = __builtin_amdgcn_mfma_f32_16x16x32_bf16(
              a1[mi], q1[ni], acc2[mi][ni], 0, 0, 0);
      }
    __builtin_amdgcn_s_setprio(0);
    if (kt + 2 < kTiles) {
      if constexpr (NMATS == 2) VMCNT(8); else VMCNT(6);  // kt+1 batch landed
    } else {
      VMCNT(0);
    }
    SCHED0;
    SBAR;       // buf[cur^1] ready for next iteration
  }

  // ---- epilogue ----
  int rowbase = mt * 128 + wr * 64;
  int colbase = nt * 64 + wc * 32;
#pragma unroll
  for (int mi = 0; mi < 4; ++mi) {
#pragma unroll
    for (int j = 0; j < 4; ++j) {
      int r = rowbase + mi * 16 + l4 * 4 + j;
      if (r >= cnt) continue;
      int entry = mylist[r];
      int tok = entry >> 1, slot = entry & 1;
      long crow = (long)slot * NTOK + tok;
      if constexpr (NMATS == 2) {
#pragma unroll
        for (int ni = 0; ni < 2; ++ni) {
          int c = colbase + ni * 16 + l15;
          float x1 = acc1[mi][ni][j];
          float x2 = acc2[mi][ni][j];
          float h = (x1 / (1.f + expf(-x1))) * x2;
          H[crow * (long)NF + c] = f2bf(h);
        }
      } else {
#pragma unroll
        for (int ni = 0; ni < 2; ++ni) {
          int c = colbase + ni * 16 + l15;
          Cf[crow * (long)ldc + c] = acc1[mi][ni][j];
        }
      }
    }
  }
}

// ---------------- combine: out = tw0*y0 + tw1*y1 ----------------
__global__ void combine_kernel(const float* __restrict__ ybuf,
                               const float* __restrict__ tw,
                               float* __restrict__ out) {
  int i = blockIdx.x * blockDim.x + threadIdx.x;
  const int total = NTOK * ND / 4;
  int stride = gridDim.x * blockDim.x;
  for (; i < total; i += stride) {
    int t = i >> 8;
    float w0 = tw[t * 2], w1 = tw[t * 2 + 1];
    float4 y0 = ((const float4*)ybuf)[i];
    float4 y1 = ((const float4*)(ybuf + (size_t)NTOK * ND))[i];
    float4 o;
    o.x = w0 * y0.x + w1 * y1.x;
    o.y = w0 * y0.y + w1 * y1.y;
    o.z = w0 * y0.z + w1 * y1.z;
    o.w = w0 * y0.w + w1 * y1.w;
    ((float4*)out)[i] = o;
  }
}

// ---------------- workspace layout (bytes) ----------------
// counts:   0         (256)
// list:     256       (131072)     end 131328
// tw:       131328    (32768)      end 164096
// choice:   164096    (16384)      end 180480
// hsb:      180480    (8388608)    end 8569088
// w1b:      8569088   (33554432)   end 42123520
// v1b:      42123520  (33554432)   end 75677952
// w2t:      75677952  (33554432)   end 109232384
// hbuf:     109232384 (33554432)   end 142786816
// ybuf:     142786816 (33554432)   end 176341248

extern "C" void kernel_launch(void* const* d_in, const int* in_sizes, int n_in,
                              void* d_out, int out_size, void* d_ws, size_t ws_size,
                              hipStream_t stream) {
  const float* hs = (const float*)d_in[0];
  const float* rk = (const float*)d_in[1];
  const float* w1 = (const float*)d_in[2];
  const float* v1 = (const float*)d_in[3];
  const float* w2 = (const float*)d_in[4];
  float* out = (float*)d_out;
  float* wout = out + (size_t)NTOK * ND;

  char* ws = (char*)d_ws;
  int* counts = (int*)(ws + 0);
  int* list = (int*)(ws + 256);
  float* tw = (float*)(ws + 131328);
  int* choice = (int*)(ws + 164096);
  unsigned short* hsb = (unsigned short*)(ws + 180480);
  unsigned short* w1b = (unsigned short*)(ws + 8569088);
  unsigned short* v1b = (unsigned short*)(ws + 42123520);
  unsigned short* w2t = (unsigned short*)(ws + 75677952);
  unsigned short* hbuf = (unsigned short*)(ws + 109232384);
  float* ybuf = (float*)(ws + 142786816);

  // router (also converts hs -> bf16), then list construction
  router_kernel<<<256, 64, 0, stream>>>(hs, rk, wout, tw, choice, hsb);
  build_lists<<<1, 1024, 0, stream>>>(choice, counts, list);

  // weight conversions
  cvt_bf16<<<4096, 256, 0, stream>>>(w1, w1b, (int)(EFD / 4));
  cvt_bf16<<<4096, 256, 0, stream>>>(v1, v1b, (int)(EFD / 4));
  transpose_w2<<<dim3(ND / 32, NF / 32, NE), dim3(32, 8), 0, stream>>>(w2, w2t);

  // fused pass1+2: h = silu(X@w1^T) * (X@v1^T)   (K=1024, N=2048, BN=64)
  gemm_pipe<2, 0><<<NE * 32 * 32, 256, 0, stream>>>(
      counts, list, hsb, ND, w1b, v1b, (long)NF * ND, 32, ND / 64,
      hbuf, nullptr, 0);

  // pass3: y = h @ w2t^T   (K=2048, N=1024, BN=64)
  gemm_pipe<1, 1><<<NE * 32 * 16, 256, 0, stream>>>(
      counts, list, hbuf, NF, w2t, nullptr, (long)ND * NF, 16, NF / 64,
      nullptr, ybuf, ND);

  combine_kernel<<<2048, 256, 0, stream>>>(ybuf, tw, out);
}

// Round 5
// 291.293 us; speedup vs baseline: 2.4648x; 1.0316x over previous
//
#include <hip/hip_runtime.h>
#include <stdint.h>
#include <math.h>

// Problem constants (DBRX FFN): B=2 S=2048 D=1024 E=8 F=2048 K=2
#define NB 2
#define NS 2048
#define ND 1024
#define NE 8
#define NF 2048
#define NTOK (NB*NS)          // 4096 tokens
#define EFD ((size_t)NE*NF*ND)

typedef short bf16x8 __attribute__((ext_vector_type(8)));
typedef float f32x4 __attribute__((ext_vector_type(4)));

__device__ __forceinline__ unsigned short f2bf(float f) {
  unsigned u = __float_as_uint(f);
  unsigned r = (u + 0x7FFFu + ((u >> 16) & 1u)) >> 16;
  return (unsigned short)r;
}
__device__ __forceinline__ float bf2f(unsigned short s) {
  return __uint_as_float(((unsigned)s) << 16);
}

__device__ __forceinline__ void async16(unsigned short* lds, const unsigned short* g) {
  __builtin_amdgcn_global_load_lds(
      (const __attribute__((address_space(1))) unsigned int*)g,
      (__attribute__((address_space(3))) unsigned int*)lds, 16, 0, 0);
}

#define VMCNT(n) asm volatile("s_waitcnt vmcnt(" #n ")" ::: "memory")
#define LGKM0    asm volatile("s_waitcnt lgkmcnt(0)" ::: "memory")
#define SBAR     __builtin_amdgcn_s_barrier()
#define SCHED0   __builtin_amdgcn_sched_barrier(0)

// ---------------- convert fp32 -> bf16 (vectorized) ----------------
__global__ void cvt_bf16(const float* __restrict__ src,
                         unsigned short* __restrict__ dst, int n4) {
  int i = blockIdx.x * blockDim.x + threadIdx.x;
  int stride = gridDim.x * blockDim.x;
  for (; i < n4; i += stride) {
    float4 v = ((const float4*)src)[i];
    ushort4 o;
    o.x = f2bf(v.x); o.y = f2bf(v.y); o.z = f2bf(v.z); o.w = f2bf(v.w);
    ((ushort4*)dst)[i] = o;
  }
}

// ---------------- transpose w2 (E,F,D) fp32 -> w2t (E,D,F) bf16 ----------------
__global__ void transpose_w2(const float* __restrict__ w2,
                             unsigned short* __restrict__ w2t) {
  __shared__ float tile[32][33];
  int e = blockIdx.z;
  int d0 = blockIdx.x * 32, f0 = blockIdx.y * 32;
  int tx = threadIdx.x, ty = threadIdx.y;
  const float* src = w2 + (size_t)e * NF * ND;
  unsigned short* dst = w2t + (size_t)e * ND * NF;
#pragma unroll
  for (int i = ty; i < 32; i += 8)
    tile[i][tx] = src[(size_t)(f0 + i) * ND + d0 + tx];
  __syncthreads();
#pragma unroll
  for (int i = ty; i < 32; i += 8)
    dst[(size_t)(d0 + i) * NF + f0 + tx] = f2bf(tile[tx][i]);
}

// ---------------- router: wave per 16 tokens, 4 lanes per token ----------------
__global__ void router_kernel(const float* __restrict__ hs,
                              const float* __restrict__ rk,
                              float* __restrict__ wout,   // [NTOK][NE]
                              float* __restrict__ tw,     // [NTOK][2]
                              int* __restrict__ choice,   // [NTOK] e0 | e1<<4
                              unsigned short* __restrict__ hsb) {
  int lane = threadIdx.x;            // 64
  int tt = lane & 15, part = lane >> 4;
  int t = blockIdx.x * 16 + tt;      // 256 blocks
  const float4* hrow = (const float4*)(hs + (size_t)t * ND) + part * 64;
  ushort4* hb4 = (ushort4*)(hsb + (size_t)t * ND) + part * 64;
  const float4* rk4 = (const float4*)rk + part * 512;
  float acc[NE];
#pragma unroll
  for (int e = 0; e < NE; ++e) acc[e] = 0.f;
#pragma unroll 4
  for (int i = 0; i < 64; ++i) {
    float4 x = hrow[i];
    ushort4 o;
    o.x = f2bf(x.x); o.y = f2bf(x.y); o.z = f2bf(x.z); o.w = f2bf(x.w);
    hb4[i] = o;
    float xs[4] = {x.x, x.y, x.z, x.w};
#pragma unroll
    for (int j = 0; j < 4; ++j) {
      float4 r0 = rk4[i * 8 + j * 2];
      float4 r1 = rk4[i * 8 + j * 2 + 1];
      acc[0] += xs[j] * r0.x; acc[1] += xs[j] * r0.y;
      acc[2] += xs[j] * r0.z; acc[3] += xs[j] * r0.w;
      acc[4] += xs[j] * r1.x; acc[5] += xs[j] * r1.y;
      acc[6] += xs[j] * r1.z; acc[7] += xs[j] * r1.w;
    }
  }
#pragma unroll
  for (int e = 0; e < NE; ++e) {
    acc[e] += __shfl_xor(acc[e], 16, 64);
    acc[e] += __shfl_xor(acc[e], 32, 64);
  }
  if (part == 0) {
    float mx = acc[0]; int i0 = 0;
#pragma unroll
    for (int e = 1; e < NE; ++e) if (acc[e] > mx) { mx = acc[e]; i0 = e; }
    float m2 = -3.4e38f; int i1 = 0;
#pragma unroll
    for (int e = 0; e < NE; ++e) if (e != i0 && acc[e] > m2) { m2 = acc[e]; i1 = e; }
    float p[NE]; float den = 0.f;
#pragma unroll
    for (int e = 0; e < NE; ++e) { p[e] = expf(acc[e] - mx); den += p[e]; }
    float inv = 1.f / den;
#pragma unroll
    for (int e = 0; e < NE; ++e) { p[e] *= inv; wout[t * NE + e] = p[e]; }
    float w0 = p[i0], w1 = p[i1];
    float s = 1.f / (w0 + w1);
    tw[t * 2 + 0] = w0 * s;
    tw[t * 2 + 1] = w1 * s;
    choice[t] = i0 | (i1 << 4);
  }
}

// ---------------- build per-expert token lists (single block, LDS atomics) ----
__global__ void build_lists(const int* __restrict__ choice,
                            int* __restrict__ counts,
                            int* __restrict__ list) {
  __shared__ int lcnt[NE];
  int tid = threadIdx.x;  // 1024
  if (tid < NE) lcnt[tid] = 0;
  __syncthreads();
  int4 c4 = ((const int4*)choice)[tid];
  int cs[4] = {c4.x, c4.y, c4.z, c4.w};
#pragma unroll
  for (int j = 0; j < 4; ++j) {
    int t = tid * 4 + j;
    int e0 = cs[j] & 15, e1 = (cs[j] >> 4) & 15;
    int p0 = atomicAdd(&lcnt[e0], 1);
    list[e0 * NTOK + p0] = t << 1;
    int p1 = atomicAdd(&lcnt[e1], 1);
    list[e1 * NTOK + p1] = (t << 1) | 1;
  }
  __syncthreads();
  if (tid < NE) counts[tid] = lcnt[tid];
}

// ---------------- ring-3 pipelined gathered NT GEMM -------------------------
// 256 threads = 4 waves (2M x 2N). Block tile 128x128 (per matrix), BK=32.
// Wave tile 64x64 per matrix (4x4 fragments of 16x16x32).
// Ring of 3 LDS buffers, stage-ahead-2, counted vmcnt (waits for loads issued
// 3 iterations back), 2 barriers/iter.
// Swizzle: LDS row = 64B = 4 chunks of 16B; slot = chunk ^ ((row>>1)&3),
// applied inverse on global source (linear LDS dest) and forward on ds_read.
// NMATS=2: B1,B2 -> h = silu(x1)*x2 -> bf16 H.  NMATS=1: B1 -> fp32 Cf.
template <int NMATS, int AROW>
__global__ __launch_bounds__(256, 2) void gemm_pipe(
    const int* __restrict__ counts, const int* __restrict__ list,
    const unsigned short* __restrict__ A, int lda,
    const unsigned short* __restrict__ B1, const unsigned short* __restrict__ B2,
    long bStrideE, int nTiles, int kTiles,
    unsigned short* __restrict__ H,
    float* __restrict__ Cf, int ldc) {
  int bid = blockIdx.x;
  int e = bid / (32 * nTiles);
  int rem = bid - e * 32 * nTiles;
  int mt = rem / nTiles;
  int nt = rem - mt * nTiles;
  int cnt = counts[e];
  if (mt * 128 >= cnt) return;

  // per buffer: A 128x32 (8KB) + B NMATS x 128x32 (8/16KB)
  constexpr int BUFE = 128 * 32 * (1 + NMATS);
  __shared__ unsigned short lds[3][BUFE];

  int tid = threadIdx.x;
  int wid = tid >> 6, lane = tid & 63;
  int wr = wid >> 1, wc = wid & 1;
  int l15 = lane & 15, l4 = lane >> 4;
  const int* mylist = list + e * NTOK;

  // ---- staging source pointers (inverse-swizzled global, linear LDS dest) ----
  // thread t fills LDS byte t*16 of each 4KB half; row = t>>2, chunk slot = t&3
  int srow = tid >> 2;                        // 0..63
  int co = ((tid & 3) ^ ((tid >> 3) & 3)) * 8; // logical elem offset for slot
  const unsigned short* aS0;
  const unsigned short* aS1;
  {
    int r0 = mt * 128 + srow;
    int r1 = r0 + 64;
    if (r0 >= cnt) r0 = cnt - 1;
    if (r1 >= cnt) r1 = cnt - 1;
    int e0 = mylist[r0], e1 = mylist[r1];
    long a0 = AROW ? ((long)(e0 & 1) * NTOK + (e0 >> 1)) : (long)(e0 >> 1);
    long a1 = AROW ? ((long)(e1 & 1) * NTOK + (e1 >> 1)) : (long)(e1 >> 1);
    aS0 = A + a0 * lda + co;
    aS1 = A + a1 * lda + co;
  }
  const unsigned short* b1S0 = B1 + (long)e * bStrideE + (long)(nt * 128 + srow) * lda + co;
  const unsigned short* b1S1 = b1S0 + (long)64 * lda;
  const unsigned short* b2S0 = nullptr;
  const unsigned short* b2S1 = nullptr;
  if constexpr (NMATS == 2) {
    b2S0 = B2 + (long)e * bStrideE + (long)(nt * 128 + srow) * lda + co;
    b2S1 = b2S0 + (long)64 * lda;
  }

  // ---- swizzled fragment read byte offsets ----
  int rowA[4], rowB[4];
#pragma unroll
  for (int mi = 0; mi < 4; ++mi) {
    int r = wr * 64 + mi * 16 + l15;
    rowA[mi] = r * 64 + ((l4 ^ ((r >> 1) & 3)) << 4);
  }
#pragma unroll
  for (int ni = 0; ni < 4; ++ni) {
    int r = wc * 64 + ni * 16 + l15;
    rowB[ni] = r * 64 + ((l4 ^ ((r >> 1) & 3)) << 4);
  }

  f32x4 acc1[4][4], acc2[4][4];
#pragma unroll
  for (int mi = 0; mi < 4; ++mi)
#pragma unroll
    for (int ni = 0; ni < 4; ++ni) {
      f32x4 z = {0.f, 0.f, 0.f, 0.f};
      acc1[mi][ni] = z;
      if constexpr (NMATS == 2) acc2[mi][ni] = z;
    }

  auto STAGE = [&](int c, int kt) {
    int ko = kt * 32;
    unsigned short* base = &lds[c][wid * 512];
    async16(base,                 aS0 + ko);
    async16(base + 2048,          aS1 + ko);
    async16(base + 4096,          b1S0 + ko);
    async16(base + 6144,          b1S1 + ko);
    if constexpr (NMATS == 2) {
      async16(base + 8192,        b2S0 + ko);
      async16(base + 10240,       b2S1 + ko);
    }
  };

  STAGE(0, 0);
  STAGE(1, 1);
  STAGE(2, 2);

  int cur = 0;
  for (int kt = 0; kt < kTiles; ++kt) {
    // wait for stage kt to have landed (issued 3 iterations back)
    if (kt + 2 < kTiles) {
      if constexpr (NMATS == 2) VMCNT(12); else VMCNT(8);
    } else if (kt + 1 < kTiles) {
      if constexpr (NMATS == 2) VMCNT(6); else VMCNT(4);
    } else {
      VMCNT(0);
    }
    SCHED0;
    SBAR;                       // all waves' portions of buf[cur] landed

    const char* la = (const char*)&lds[cur][0];
    const char* lb1 = la + 8192;
    const char* lb2 = la + 16384;
    bf16x8 a[4], b1[4], b2[4];
#pragma unroll
    for (int mi = 0; mi < 4; ++mi)
      a[mi] = *(const bf16x8*)(la + rowA[mi]);
#pragma unroll
    for (int ni = 0; ni < 4; ++ni) {
      b1[ni] = *(const bf16x8*)(lb1 + rowB[ni]);
      if constexpr (NMATS == 2)
        b2[ni] = *(const bf16x8*)(lb2 + rowB[ni]);
    }
    LGKM0;                      // my reads complete
    SCHED0;
    SBAR;                       // ALL waves' reads of buf[cur] complete
    if (kt + 3 < kTiles) STAGE(cur, kt + 3);   // refill just-freed buffer

    __builtin_amdgcn_s_setprio(1);
#pragma unroll
    for (int mi = 0; mi < 4; ++mi)
#pragma unroll
      for (int ni = 0; ni < 4; ++ni) {
        acc1[mi][ni] = __builtin_amdgcn_mfma_f32_16x16x32_bf16(
            a[mi], b1[ni], acc1[mi][ni], 0, 0, 0);
        if constexpr (NMATS == 2)
          acc2[mi][ni] = __builtin_amdgcn_mfma_f32_16x16x32_bf16(
              a[mi], b2[ni], acc2[mi][ni], 0, 0, 0);
      }
    __builtin_amdgcn_s_setprio(0);

    cur = (cur == 2) ? 0 : cur + 1;
  }

  // ---- epilogue ----
  int rowbase = mt * 128 + wr * 64;
  int colbase = nt * 128 + wc * 64;
#pragma unroll
  for (int mi = 0; mi < 4; ++mi) {
#pragma unroll
    for (int j = 0; j < 4; ++j) {
      int r = rowbase + mi * 16 + l4 * 4 + j;
      if (r >= cnt) continue;
      int entry = mylist[r];
      int tok = entry >> 1, slot = entry & 1;
      long crow = (long)slot * NTOK + tok;
      if constexpr (NMATS == 2) {
#pragma unroll
        for (int ni = 0; ni < 4; ++ni) {
          int c = colbase + ni * 16 + l15;
          float x1 = acc1[mi][ni][j];
          float x2 = acc2[mi][ni][j];
          float h = (x1 / (1.f + expf(-x1))) * x2;
          H[crow * (long)NF + c] = f2bf(h);
        }
      } else {
#pragma unroll
        for (int ni = 0; ni < 4; ++ni) {
          int c = colbase + ni * 16 + l15;
          Cf[crow * (long)ldc + c] = acc1[mi][ni][j];
        }
      }
    }
  }
}

// ---------------- combine: out = tw0*y0 + tw1*y1 ----------------
__global__ void combine_kernel(const float* __restrict__ ybuf,
                               const float* __restrict__ tw,
                               float* __restrict__ out) {
  int i = blockIdx.x * blockDim.x + threadIdx.x;
  const int total = NTOK * ND / 4;
  int stride = gridDim.x * blockDim.x;
  for (; i < total; i += stride) {
    int t = i >> 8;
    float w0 = tw[t * 2], w1 = tw[t * 2 + 1];
    float4 y0 = ((const float4*)ybuf)[i];
    float4 y1 = ((const float4*)(ybuf + (size_t)NTOK * ND))[i];
    float4 o;
    o.x = w0 * y0.x + w1 * y1.x;
    o.y = w0 * y0.y + w1 * y1.y;
    o.z = w0 * y0.z + w1 * y1.z;
    o.w = w0 * y0.w + w1 * y1.w;
    ((float4*)out)[i] = o;
  }
}

// ---------------- workspace layout (bytes) ----------------
// counts:   0         (256)
// list:     256       (131072)     end 131328
// tw:       131328    (32768)      end 164096
// choice:   164096    (16384)      end 180480
// hsb:      180480    (8388608)    end 8569088
// w1b:      8569088   (33554432)   end 42123520
// v1b:      42123520  (33554432)   end 75677952
// w2t:      75677952  (33554432)   end 109232384
// hbuf:     109232384 (33554432)   end 142786816
// ybuf:     142786816 (33554432)   end 176341248

extern "C" void kernel_launch(void* const* d_in, const int* in_sizes, int n_in,
                              void* d_out, int out_size, void* d_ws, size_t ws_size,
                              hipStream_t stream) {
  const float* hs = (const float*)d_in[0];
  const float* rk = (const float*)d_in[1];
  const float* w1 = (const float*)d_in[2];
  const float* v1 = (const float*)d_in[3];
  const float* w2 = (const float*)d_in[4];
  float* out = (float*)d_out;
  float* wout = out + (size_t)NTOK * ND;

  char* ws = (char*)d_ws;
  int* counts = (int*)(ws + 0);
  int* list = (int*)(ws + 256);
  float* tw = (float*)(ws + 131328);
  int* choice = (int*)(ws + 164096);
  unsigned short* hsb = (unsigned short*)(ws + 180480);
  unsigned short* w1b = (unsigned short*)(ws + 8569088);
  unsigned short* v1b = (unsigned short*)(ws + 42123520);
  unsigned short* w2t = (unsigned short*)(ws + 75677952);
  unsigned short* hbuf = (unsigned short*)(ws + 109232384);
  float* ybuf = (float*)(ws + 142786816);

  // router (also converts hs -> bf16), then list construction
  router_kernel<<<256, 64, 0, stream>>>(hs, rk, wout, tw, choice, hsb);
  build_lists<<<1, 1024, 0, stream>>>(choice, counts, list);

  // weight conversions
  cvt_bf16<<<4096, 256, 0, stream>>>(w1, w1b, (int)(EFD / 4));
  cvt_bf16<<<4096, 256, 0, stream>>>(v1, v1b, (int)(EFD / 4));
  transpose_w2<<<dim3(ND / 32, NF / 32, NE), dim3(32, 8), 0, stream>>>(w2, w2t);

  // fused pass1+2: h = silu(X@w1^T) * (X@v1^T)   (K=1024, BN=128 per mat)
  gemm_pipe<2, 0><<<NE * 32 * 16, 256, 0, stream>>>(
      counts, list, hsb, ND, w1b, v1b, (long)NF * ND, 16, ND / 32,
      hbuf, nullptr, 0);

  // pass3: y = h @ w2t^T   (K=2048, BN=128)
  gemm_pipe<1, 1><<<NE * 32 * 8, 256, 0, stream>>>(
      counts, list, hbuf, NF, w2t, nullptr, (long)ND * NF, 8, NF / 32,
      nullptr, ybuf, ND);

  combine_kernel<<<2048, 256, 0, stream>>>(ybuf, tw, out);
}